// Round 1
// baseline (1443.715 us; speedup 1.0000x reference)
//
#include <hip/hip_runtime.h>

#define E_EDGES 500000
#define N_NODES 30000
#define GRID    1024
#define NTHREAD 262144   // GRID * 256

typedef float  floatx4 __attribute__((ext_vector_type(4)));
typedef short  shortx4 __attribute__((ext_vector_type(4)));
typedef short  shortx8 __attribute__((ext_vector_type(8)));
typedef __bf16 bf16x8  __attribute__((ext_vector_type(8)));

__device__ inline short f2bf(float f) {
    unsigned u = __builtin_bit_cast(unsigned, f);
    u += 0x7fffu + ((u >> 16) & 1u);        // round-to-nearest-even
    return (short)(u >> 16);
}
__device__ inline float bf2f(short s) {
    unsigned u = ((unsigned)(unsigned short)s) << 16;
    return __builtin_bit_cast(float, u);
}

// Device-wide barrier. Safe because the whole grid (1024 blocks) is
// co-resident by construction: 33.8 KB static LDS -> <=4 blocks/CU from LDS,
// __launch_bounds__(256,4) forces VGPR<=128 -> 4 blocks/CU guaranteed,
// 4 * 256 CUs = 1024 blocks. atomicAdd is device-scope by default;
// __threadfence() is an agent-scope fence (L2 wb/inv on gfx950).
__device__ inline void gbar(int* ctr, int nblk) {
    __syncthreads();
    if (threadIdx.x == 0) {
        __threadfence();                       // release: publish prior writes
        atomicAdd(ctr, 1);
        int it = 0;
        while (__hip_atomic_load(ctr, __ATOMIC_RELAXED, __HIP_MEMORY_SCOPE_AGENT) < nblk) {
            __builtin_amdgcn_s_sleep(2);
            if (++it > (1 << 22)) break;       // bail out -> visible failure, no hang
        }
        __threadfence();                       // acquire: invalidate stale caches
    }
    __syncthreads();
}

__global__ __launch_bounds__(256, 4) void mega(
    const float* __restrict__ x, const float* __restrict__ rbf,
    const int* __restrict__ idx, const float* __restrict__ wrbf,
    const float* __restrict__ wup, const float* __restrict__ whid,
    const float* __restrict__ bias, const float* __restrict__ wout,
    float* __restrict__ out,
    short* __restrict__ h16, short* __restrict__ wfrag,
    int* __restrict__ edge_list, int* __restrict__ counts,
    int* __restrict__ ctrs, int* __restrict__ blocksum,
    int* __restrict__ blockbase, int* __restrict__ offsets,
    int* __restrict__ cursor)
{
    __shared__ __align__(16) short ylds[64 * 264];   // 33792 B, single buffer
    __shared__ int wpart[4];

    const int b    = blockIdx.x;
    const int t    = threadIdx.x;
    const int gtid = b * 256 + t;
    const int lane = t & 63, wave = t >> 6;

    // ---------------- P0: weight reformat to MFMA B-fragment bf16 ----------
    if (gtid < 65536) {
        int mat = gtid >> 13, grp = gtid & 8191;
        int a = mat >> 2, lay = mat & 3;
        const float* src = (lay == 0) ? (wup + a * 65536)
                                      : (whid + (a * 3 + lay - 1) * 65536);
        int ks  = grp >> 10;
        int rem = grp & 1023;
        int ntg = rem >> 6;
        int l2  = rem & 63;
        int q2 = l2 >> 4, c2 = l2 & 15;
        int col = ntg * 16 + c2;
        int k0  = ks * 32 + q2 * 8;
        shortx8 v;
#pragma unroll
        for (int j = 0; j < 8; j++) v[j] = f2bf(src[(k0 + j) * 256 + col]);
        ((shortx8*)wfrag)[gtid] = v;
    }

    // ---------------- P0b: histogram of edge target ids --------------------
    for (int e = gtid; e < E_EDGES; e += NTHREAD)
        atomicAdd(&counts[idx[e]], 1);
    gbar(ctrs + 0, GRID);

    // ---------------- P1a: per-chunk (30 nodes) exclusive scan --------------
    if (b < 1000) {
        if (wave == 0) {
            int n = b * 30 + lane;
            int c = (lane < 30) ? counts[n] : 0;
            int incl = c;
#pragma unroll
            for (int d = 1; d < 64; d <<= 1) {
                int v = __shfl_up(incl, d);
                if (lane >= d) incl += v;
            }
            if (lane < 30) offsets[n] = incl - c;     // exclusive within chunk
            if (lane == 29) blocksum[b] = incl;       // chunk total
        }
    } else if (t == 0) {
        blocksum[b] = 0;
    }
    gbar(ctrs + 1, GRID);

    // ---------------- P1b: block 0 scans the 1024 chunk totals --------------
    if (b == 0) {
        int4 v = ((const int4*)blocksum)[t];
        int s1 = v.x + v.y, s2 = s1 + v.z, tot = s2 + v.w;
        int incl = tot;
#pragma unroll
        for (int d = 1; d < 64; d <<= 1) {
            int u = __shfl_up(incl, d);
            if (lane >= d) incl += u;
        }
        if (lane == 63) wpart[wave] = incl;
        __syncthreads();
        int base = 0;
#pragma unroll
        for (int k = 0; k < 4; k++) if (k < wave) base += wpart[k];
        int excl = base + incl - tot;
        int4 o;
        o.x = excl; o.y = excl + v.x; o.z = excl + s1; o.w = excl + s2;
        ((int4*)blockbase)[t] = o;
    }
    gbar(ctrs + 2, GRID);

    // ---------------- P1c: add chunk bases, init cursor ---------------------
    if (b < 1000 && wave == 0 && lane < 30) {
        int n = b * 30 + lane;
        int o = offsets[n] + blockbase[b];
        offsets[n] = o;
        cursor[n]  = o;
    }
    if (gtid == 0) offsets[N_NODES] = E_EDGES;
    gbar(ctrs + 3, GRID);

    // ---------------- P2: scatter edge ids into CSR order -------------------
    for (int e = gtid; e < E_EDGES; e += NTHREAD) {
        int pos = atomicAdd(&cursor[idx[e]], 1);
        edge_list[pos] = e;
    }
    gbar(ctrs + 4, GRID);

    // ---------------- P3: gather, one node per wave, h stored as bf16 -------
    {
        const floatx4* wr4 = (const floatx4*)wrbf;    // [6][64] float4
        floatx4 wr[6];
#pragma unroll
        for (int k = 0; k < 6; k++) wr[k] = wr4[k * 64 + lane];

        for (int node = b * 4 + wave; node < N_NODES; node += 4096) {
            int beg = offsets[node], end = offsets[node + 1];
            floatx4 acc = {0.f, 0.f, 0.f, 0.f};
            for (int j = beg; j < end; j++) {
                int e = edge_list[j];
                float r0 = rbf[e * 6 + 0], r1 = rbf[e * 6 + 1], r2 = rbf[e * 6 + 2];
                float r3 = rbf[e * 6 + 3], r4 = rbf[e * 6 + 4], r5 = rbf[e * 6 + 5];
                floatx4 xv = __builtin_nontemporal_load(
                    &((const floatx4*)x)[(size_t)e * 64 + lane]);
                floatx4 p = r0 * wr[0] + r1 * wr[1] + r2 * wr[2]
                          + r3 * wr[3] + r4 * wr[4] + r5 * wr[5];
                acc += p * xv;
            }
            shortx4 s4 = { f2bf(acc.x), f2bf(acc.y), f2bf(acc.z), f2bf(acc.w) };
            ((shortx4*)h16)[(size_t)node * 64 + lane] = s4;
        }
    }
    gbar(ctrs + 5, GRID);

    // ---------------- P4: fused MLP, one (a, 64-row tile) per block ---------
    const int q = lane >> 4, c15 = lane & 15;
    for (int tile = b; tile < 938; tile += GRID) {
        const int a  = tile & 1;
        const int n0 = (tile >> 1) * 64;

        // stage h tile (already bf16) into LDS
#pragma unroll
        for (int j = 0; j < 8; j++) {
            int grp = t + j * 256;
            int r = grp >> 5, c8 = grp & 31;
            shortx8 v = {0, 0, 0, 0, 0, 0, 0, 0};
            if (n0 + r < N_NODES)
                v = *(const shortx8*)&h16[(size_t)(n0 + r) * 256 + c8 * 8];
            *(shortx8*)&ylds[r * 264 + c8 * 8] = v;
        }
        __syncthreads();

        for (int lay = 0; lay < 4; lay++) {
            const bf16x8* wf = (const bf16x8*)(wfrag + (size_t)(a * 4 + lay) * 65536);
            floatx4 acc[4][4];
#pragma unroll
            for (int mt = 0; mt < 4; mt++)
#pragma unroll
                for (int nt = 0; nt < 4; nt++)
                    acc[mt][nt] = (floatx4){0.f, 0.f, 0.f, 0.f};

#pragma unroll
            for (int ks = 0; ks < 8; ks++) {
                bf16x8 bfr[4];
#pragma unroll
                for (int nt = 0; nt < 4; nt++)
                    bfr[nt] = wf[(ks * 16 + wave * 4 + nt) * 64 + lane];
#pragma unroll
                for (int mt = 0; mt < 4; mt++) {
                    bf16x8 afr = *(const bf16x8*)&ylds[(mt * 16 + c15) * 264 + ks * 32 + q * 8];
#pragma unroll
                    for (int nt = 0; nt < 4; nt++)
                        acc[mt][nt] = __builtin_amdgcn_mfma_f32_16x16x32_bf16(
                            afr, bfr[nt], acc[mt][nt], 0, 0, 0);
                }
            }
            __syncthreads();              // all reads done before overwrite

            float bv[4];
#pragma unroll
            for (int nt = 0; nt < 4; nt++)
                bv[nt] = (lay >= 1)
                       ? bias[(a * 3 + lay - 1) * 256 + wave * 64 + nt * 16 + c15]
                       : 0.0f;
#pragma unroll
            for (int mt = 0; mt < 4; mt++)
#pragma unroll
                for (int nt = 0; nt < 4; nt++)
#pragma unroll
                    for (int rg = 0; rg < 4; rg++) {
                        float v = acc[mt][nt][rg] + bv[nt];
                        if (lay >= 1) v = v / (1.0f + __expf(-v));   // SiLU
                        ylds[(mt * 16 + q * 4 + rg) * 264 + wave * 64 + nt * 16 + c15] = f2bf(v);
                    }
            __syncthreads();
        }

        // output projection: y3[64][256] . wout[a][256], vectorized LDS reads
        {
            int r  = wave * 16 + (lane >> 2);
            int cq = lane & 3;
            const float* wo = wout + a * 256 + cq * 64;
            const short* yp = &ylds[r * 264 + cq * 64];
            float s = 0.0f;
#pragma unroll
            for (int bb = 0; bb < 8; bb++) {
                shortx8 v = *(const shortx8*)&yp[bb * 8];
#pragma unroll
                for (int j = 0; j < 8; j++) s += bf2f(v[j]) * wo[bb * 8 + j];
            }
            s += __shfl_xor(s, 1);
            s += __shfl_xor(s, 2);
            if (cq == 0 && n0 + r < N_NODES) out[a * N_NODES + n0 + r] = s;
        }
        __syncthreads();
    }
}

// ---------------------------------------------------------------------------
extern "C" void kernel_launch(void* const* d_in, const int* in_sizes, int n_in,
                              void* d_out, int out_size, void* d_ws, size_t ws_size,
                              hipStream_t stream)
{
    (void)in_sizes; (void)n_in; (void)out_size; (void)ws_size;
    const float* x    = (const float*)d_in[0];
    const float* rbf  = (const float*)d_in[1];
    const int*   idx  = (const int*)d_in[2];
    const float* wrbf = (const float*)d_in[4];
    const float* wup  = (const float*)d_in[5];
    const float* whid = (const float*)d_in[6];
    const float* bias = (const float*)d_in[7];
    const float* wout = (const float*)d_in[8];
    float* out = (float*)d_out;

    char* ws = (char*)d_ws;
    short* h16       = (short*)ws;  ws += (size_t)N_NODES * 256 * sizeof(short); // 15,360,000
    short* wfrag     = (short*)ws;  ws += (size_t)8 * 65536 * sizeof(short);     //  1,048,576
    int*   edge_list = (int*)ws;    ws += (size_t)E_EDGES * sizeof(int);         //  2,000,000
    int*   counts    = (int*)ws;    ws += (size_t)N_NODES * sizeof(int);         //    120,000
    int*   ctrs      = (int*)ws;    ws += 8 * sizeof(int);                       //         32
    int*   blocksum  = (int*)ws;    ws += 1024 * sizeof(int);                    // 16B-aligned
    int*   blockbase = (int*)ws;    ws += 1024 * sizeof(int);
    int*   offsets   = (int*)ws;    ws += (size_t)(N_NODES + 1) * sizeof(int);
    int*   cursor    = (int*)ws;

    // zero histogram counters AND barrier counters (contiguous) every launch
    hipMemsetAsync(counts, 0, (size_t)(N_NODES + 8) * sizeof(int), stream);
    mega<<<GRID, 256, 0, stream>>>(x, rbf, idx, wrbf, wup, whid, bias, wout, out,
                                   h16, wfrag, edge_list, counts, ctrs,
                                   blocksum, blockbase, offsets, cursor);
}

// Round 2
// 830.621 us; speedup vs baseline: 1.7381x; 1.7381x over previous
//
#include <hip/hip_runtime.h>

#define E_EDGES 500000
#define N_NODES 30000
#define H_DIM   256

typedef float  floatx4 __attribute__((ext_vector_type(4)));
typedef short  shortx4 __attribute__((ext_vector_type(4)));
typedef short  shortx8 __attribute__((ext_vector_type(8)));
typedef __bf16 bf16x8  __attribute__((ext_vector_type(8)));

__device__ inline short f2bf(float f) {
    unsigned u = __builtin_bit_cast(unsigned, f);
    u += 0x7fffu + ((u >> 16) & 1u);        // round-to-nearest-even
    return (short)(u >> 16);
}
__device__ inline float bf2f(short s) {
    unsigned u = ((unsigned)(unsigned short)s) << 16;
    return __builtin_bit_cast(float, u);
}

// ---------------------------------------------------------------------------
// Reformat W_up / W_hidden into MFMA B-fragment-major bf16.
// ---------------------------------------------------------------------------
__global__ __launch_bounds__(256) void prep_weights(
    const float* __restrict__ wup, const float* __restrict__ whid,
    short* __restrict__ wfrag)
{
    int g   = blockIdx.x * 256 + threadIdx.x;   // 0..65535
    int mat = g >> 13;
    int grp = g & 8191;
    int a = mat >> 2, lay = mat & 3;
    const float* src = (lay == 0) ? (wup + a * 65536)
                                  : (whid + (a * 3 + lay - 1) * 65536);
    int ks  = grp >> 10;
    int rem = grp & 1023;
    int ntg = rem >> 6;
    int lane = rem & 63;
    int q = lane >> 4, c = lane & 15;
    int col = ntg * 16 + c;
    int k0  = ks * 32 + q * 8;
    shortx8 v;
#pragma unroll
    for (int j = 0; j < 8; j++) v[j] = f2bf(src[(k0 + j) * 256 + col]);
    ((shortx8*)wfrag)[g] = v;
}

// ---------------------------------------------------------------------------
// CSR build: histogram -> exclusive scan -> id scatter.
// ---------------------------------------------------------------------------
__global__ __launch_bounds__(256) void hist_kernel(
    const int* __restrict__ idx, int* __restrict__ counts)
{
    int e = blockIdx.x * 256 + threadIdx.x;
    if (e < E_EDGES) atomicAdd(&counts[idx[e]], 1);
}

__global__ __launch_bounds__(1024) void scan_kernel(
    const int* __restrict__ counts, int* __restrict__ offsets,
    int* __restrict__ cursor)
{
    const int t = threadIdx.x;                  // 1024 threads, chunk = 30
    const int lane = t & 63, wave = t >> 6;
    const int base = t * 30;
    int local[30];
    int s = 0;
#pragma unroll
    for (int j = 0; j < 30; j++) {
        int c = (base + j < N_NODES) ? counts[base + j] : 0;
        local[j] = s;                           // exclusive within chunk
        s += c;
    }
    // inclusive wave scan of s
    int incl = s;
#pragma unroll
    for (int d = 1; d < 64; d <<= 1) {
        int v = __shfl_up(incl, d);
        if (lane >= d) incl += v;
    }
    __shared__ int part[16];
    if (lane == 63) part[wave] = incl;
    __syncthreads();
    if (t == 0) {
        int run = 0;
#pragma unroll
        for (int k = 0; k < 16; k++) { int v = part[k]; part[k] = run; run += v; }
    }
    __syncthreads();
    int excl = part[wave] + incl - s;           // exclusive base for this thread
#pragma unroll
    for (int j = 0; j < 30; j++) {
        int n = base + j;
        if (n < N_NODES) { offsets[n] = excl + local[j]; cursor[n] = excl + local[j]; }
    }
    if (t == 1023) offsets[N_NODES] = E_EDGES; // grand total = E_EDGES
}

__global__ __launch_bounds__(256) void scatter_ids(
    const int* __restrict__ idx, int* __restrict__ cursor,
    int* __restrict__ edge_list)
{
    int e = blockIdx.x * 256 + threadIdx.x;
    if (e >= E_EDGES) return;
    int pos = atomicAdd(&cursor[idx[e]], 1);
    edge_list[pos] = e;
}

// ---------------------------------------------------------------------------
// Gather: one wave per node, h written as bf16.
// Edge ids prefetched 64-at-a-time with one coalesced load, then shfl'd out,
// so the per-edge rbf/x loads are address-independent and pipeline under
// vmcnt instead of forming a load->load dependent chain.
// ---------------------------------------------------------------------------
__global__ __launch_bounds__(256) void gather_nodes(
    const float* __restrict__ x, const float* __restrict__ rbf,
    const int* __restrict__ edge_list, const int* __restrict__ offsets,
    const float* __restrict__ wrbf, short* __restrict__ h16)
{
    int node = blockIdx.x * 4 + (threadIdx.x >> 6);
    if (node >= N_NODES) return;
    int lane = threadIdx.x & 63;

    const floatx4* wr4 = (const floatx4*)wrbf;   // [6][64] float4
    floatx4 wr[6];
#pragma unroll
    for (int k = 0; k < 6; k++) wr[k] = wr4[k * 64 + lane];

    int beg = offsets[node], end = offsets[node + 1];
    floatx4 acc = {0.f, 0.f, 0.f, 0.f};
    for (int j0 = beg; j0 < end; j0 += 64) {
        int myid = (j0 + lane < end) ? edge_list[j0 + lane] : 0;  // coalesced
        int cnt  = end - j0; if (cnt > 64) cnt = 64;
#pragma unroll 2
        for (int g = 0; g < cnt; g++) {
            int e = __shfl(myid, g);
            float r0 = rbf[e * 6 + 0], r1 = rbf[e * 6 + 1], r2 = rbf[e * 6 + 2];
            float r3 = rbf[e * 6 + 3], r4 = rbf[e * 6 + 4], r5 = rbf[e * 6 + 5];
            floatx4 xv = __builtin_nontemporal_load(
                &((const floatx4*)x)[(size_t)e * 64 + lane]);
            floatx4 p = r0 * wr[0] + r1 * wr[1] + r2 * wr[2]
                      + r3 * wr[3] + r4 * wr[4] + r5 * wr[5];
            acc += p * xv;
        }
    }
    shortx4 s4 = { f2bf(acc.x), f2bf(acc.y), f2bf(acc.z), f2bf(acc.w) };
    ((shortx4*)h16)[(size_t)node * 64 + lane] = s4;
}

// ---------------------------------------------------------------------------
// Fused MLP: one (a, 64-row tile) per block. Single 33.8 KB LDS buffer,
// h read as bf16, vectorized LDS reads in the output projection.
// ---------------------------------------------------------------------------
__global__ __launch_bounds__(256, 2) void mlp_kernel(
    const short* __restrict__ h16, const short* __restrict__ wfrag,
    const float* __restrict__ bias, const float* __restrict__ wout,
    float* __restrict__ out)
{
    __shared__ __align__(16) short ylds[64 * 264];
    const int t = threadIdx.x;
    const int wave = t >> 6, lane = t & 63, q = lane >> 4, c15 = lane & 15;
    const int a  = blockIdx.x & 1;
    const int n0 = (blockIdx.x >> 1) * 64;

    // stage h tile (already bf16) into LDS
#pragma unroll
    for (int j = 0; j < 8; j++) {
        int grp = t + j * 256;
        int r = grp >> 5, c8 = grp & 31;
        shortx8 v = {0, 0, 0, 0, 0, 0, 0, 0};
        if (n0 + r < N_NODES)
            v = *(const shortx8*)&h16[(size_t)(n0 + r) * 256 + c8 * 8];
        *(shortx8*)&ylds[r * 264 + c8 * 8] = v;
    }
    __syncthreads();

    for (int lay = 0; lay < 4; lay++) {
        const bf16x8* wf = (const bf16x8*)(wfrag + (size_t)(a * 4 + lay) * 65536);
        floatx4 acc[4][4];
#pragma unroll
        for (int mt = 0; mt < 4; mt++)
#pragma unroll
            for (int nt = 0; nt < 4; nt++)
                acc[mt][nt] = (floatx4){0.f, 0.f, 0.f, 0.f};

#pragma unroll
        for (int ks = 0; ks < 8; ks++) {
            bf16x8 bfr[4];
#pragma unroll
            for (int nt = 0; nt < 4; nt++)
                bfr[nt] = wf[(ks * 16 + wave * 4 + nt) * 64 + lane];
#pragma unroll
            for (int mt = 0; mt < 4; mt++) {
                bf16x8 afr = *(const bf16x8*)&ylds[(mt * 16 + c15) * 264 + ks * 32 + q * 8];
#pragma unroll
                for (int nt = 0; nt < 4; nt++)
                    acc[mt][nt] = __builtin_amdgcn_mfma_f32_16x16x32_bf16(
                        afr, bfr[nt], acc[mt][nt], 0, 0, 0);
            }
        }
        __syncthreads();              // all reads done before overwrite

        float bv[4];
#pragma unroll
        for (int nt = 0; nt < 4; nt++)
            bv[nt] = (lay >= 1)
                   ? bias[(a * 3 + lay - 1) * 256 + wave * 64 + nt * 16 + c15]
                   : 0.0f;
#pragma unroll
        for (int mt = 0; mt < 4; mt++)
#pragma unroll
            for (int nt = 0; nt < 4; nt++)
#pragma unroll
                for (int rg = 0; rg < 4; rg++) {
                    float v = acc[mt][nt][rg] + bv[nt];
                    if (lay >= 1) v = v / (1.0f + __expf(-v));   // SiLU
                    ylds[(mt * 16 + q * 4 + rg) * 264 + wave * 64 + nt * 16 + c15] = f2bf(v);
                }
        __syncthreads();
    }

    // output projection: y3[64][256] . wout[a][256], vectorized LDS reads
    {
        int r  = wave * 16 + (lane >> 2);
        int cq = lane & 3;
        const float* wo = wout + a * 256 + cq * 64;
        const short* yp = &ylds[r * 264 + cq * 64];
        float s = 0.0f;
#pragma unroll
        for (int bb = 0; bb < 8; bb++) {
            shortx8 v = *(const shortx8*)&yp[bb * 8];
#pragma unroll
            for (int j = 0; j < 8; j++) s += bf2f(v[j]) * wo[bb * 8 + j];
        }
        s += __shfl_xor(s, 1);
        s += __shfl_xor(s, 2);
        if (cq == 0 && n0 + r < N_NODES) out[a * N_NODES + n0 + r] = s;
    }
}

// ---------------------------------------------------------------------------
extern "C" void kernel_launch(void* const* d_in, const int* in_sizes, int n_in,
                              void* d_out, int out_size, void* d_ws, size_t ws_size,
                              hipStream_t stream)
{
    (void)in_sizes; (void)n_in; (void)out_size; (void)ws_size;
    const float* x    = (const float*)d_in[0];
    const float* rbf  = (const float*)d_in[1];
    const int*   idx  = (const int*)d_in[2];
    const float* wrbf = (const float*)d_in[4];
    const float* wup  = (const float*)d_in[5];
    const float* whid = (const float*)d_in[6];
    const float* bias = (const float*)d_in[7];
    const float* wout = (const float*)d_in[8];
    float* out = (float*)d_out;

    char* ws = (char*)d_ws;
    short* h16       = (short*)ws;  ws += (size_t)N_NODES * H_DIM * sizeof(short);
    short* wfrag     = (short*)ws;  ws += (size_t)8 * 65536 * sizeof(short);
    int*   counts    = (int*)ws;    ws += (size_t)N_NODES * sizeof(int);
    int*   offsets   = (int*)ws;    ws += (size_t)(N_NODES + 1) * sizeof(int);
    int*   cursor    = (int*)ws;    ws += (size_t)N_NODES * sizeof(int);
    int*   edge_list = (int*)ws;

    hipMemsetAsync(counts, 0, (size_t)N_NODES * sizeof(int), stream);
    prep_weights<<<256, 256, 0, stream>>>(wup, whid, wfrag);
    hist_kernel<<<(E_EDGES + 255) / 256, 256, 0, stream>>>(idx, counts);
    scan_kernel<<<1, 1024, 0, stream>>>(counts, offsets, cursor);
    scatter_ids<<<(E_EDGES + 255) / 256, 256, 0, stream>>>(idx, cursor, edge_list);
    gather_nodes<<<(N_NODES + 3) / 4, 256, 0, stream>>>(x, rbf, edge_list, offsets, wrbf, h16);
    mlp_kernel<<<938, 256, 0, stream>>>(h16, wfrag, bias, wout, out);
}

// Round 3
// 828.549 us; speedup vs baseline: 1.7425x; 1.0025x over previous
//
#include <hip/hip_runtime.h>

#define E_EDGES 500000
#define N_NODES 30000
#define H_DIM   256

typedef float  floatx4 __attribute__((ext_vector_type(4)));
typedef float  floatx2 __attribute__((ext_vector_type(2)));
typedef short  shortx4 __attribute__((ext_vector_type(4)));
typedef short  shortx8 __attribute__((ext_vector_type(8)));
typedef __bf16 bf16x8  __attribute__((ext_vector_type(8)));

__device__ inline short f2bf(float f) {
    unsigned u = __builtin_bit_cast(unsigned, f);
    u += 0x7fffu + ((u >> 16) & 1u);        // round-to-nearest-even
    return (short)(u >> 16);
}
__device__ inline float bf2f(short s) {
    unsigned u = ((unsigned)(unsigned short)s) << 16;
    return __builtin_bit_cast(float, u);
}

// ---------------------------------------------------------------------------
// Fused: blocks [0,256) reformat W_up/W_hidden into MFMA B-fragment bf16;
// blocks [256,745) histogram edge target ids with int4-vectorized reads.
// The two jobs are independent -> overlap in one dispatch.
// ---------------------------------------------------------------------------
__global__ __launch_bounds__(256) void prep_hist(
    const float* __restrict__ wup, const float* __restrict__ whid,
    short* __restrict__ wfrag,
    const int* __restrict__ idx, int* __restrict__ counts)
{
    const int b = blockIdx.x;
    if (b < 256) {
        int g   = b * 256 + threadIdx.x;        // 0..65535
        int mat = g >> 13;
        int grp = g & 8191;
        int a = mat >> 2, lay = mat & 3;
        const float* src = (lay == 0) ? (wup + a * 65536)
                                      : (whid + (a * 3 + lay - 1) * 65536);
        int ks  = grp >> 10;
        int rem = grp & 1023;
        int ntg = rem >> 6;
        int lane = rem & 63;
        int q = lane >> 4, c = lane & 15;
        int col = ntg * 16 + c;
        int k0  = ks * 32 + q * 8;
        shortx8 v;
#pragma unroll
        for (int j = 0; j < 8; j++) v[j] = f2bf(src[(k0 + j) * 256 + col]);
        ((shortx8*)wfrag)[g] = v;
    } else {
        int g = (b - 256) * 256 + threadIdx.x;  // one int4 = 4 edges
        if (g < E_EDGES / 4) {
            int4 v = ((const int4*)idx)[g];
            atomicAdd(&counts[v.x], 1);
            atomicAdd(&counts[v.y], 1);
            atomicAdd(&counts[v.z], 1);
            atomicAdd(&counts[v.w], 1);
        }
    }
}

// ---------------------------------------------------------------------------
// Exclusive scan of counts -> offsets (+ cursor copy). Single block.
// ---------------------------------------------------------------------------
__global__ __launch_bounds__(1024) void scan_kernel(
    const int* __restrict__ counts, int* __restrict__ offsets,
    int* __restrict__ cursor)
{
    const int t = threadIdx.x;                  // 1024 threads, chunk = 30
    const int lane = t & 63, wave = t >> 6;
    const int base = t * 30;
    int local[30];
    int s = 0;
#pragma unroll
    for (int j = 0; j < 30; j++) {
        int c = (base + j < N_NODES) ? counts[base + j] : 0;
        local[j] = s;                           // exclusive within chunk
        s += c;
    }
    // inclusive wave scan of s
    int incl = s;
#pragma unroll
    for (int d = 1; d < 64; d <<= 1) {
        int v = __shfl_up(incl, d);
        if (lane >= d) incl += v;
    }
    __shared__ int part[16];
    if (lane == 63) part[wave] = incl;
    __syncthreads();
    if (t == 0) {
        int run = 0;
#pragma unroll
        for (int k = 0; k < 16; k++) { int v = part[k]; part[k] = run; run += v; }
    }
    __syncthreads();
    int excl = part[wave] + incl - s;           // exclusive base for this thread
#pragma unroll
    for (int j = 0; j < 30; j++) {
        int n = base + j;
        if (n < N_NODES) { offsets[n] = excl + local[j]; cursor[n] = excl + local[j]; }
    }
    if (t == 1023) offsets[N_NODES] = E_EDGES; // grand total = E_EDGES
}

// ---------------------------------------------------------------------------
// Scatter edge ids into CSR order, int4-vectorized idx reads.
// ---------------------------------------------------------------------------
__global__ __launch_bounds__(256) void scatter_ids(
    const int* __restrict__ idx, int* __restrict__ cursor,
    int* __restrict__ edge_list)
{
    int g = blockIdx.x * 256 + threadIdx.x;
    if (g >= E_EDGES / 4) return;
    int4 v = ((const int4*)idx)[g];
    int e0 = g * 4;
    int p0 = atomicAdd(&cursor[v.x], 1); edge_list[p0] = e0 + 0;
    int p1 = atomicAdd(&cursor[v.y], 1); edge_list[p1] = e0 + 1;
    int p2 = atomicAdd(&cursor[v.z], 1); edge_list[p2] = e0 + 2;
    int p3 = atomicAdd(&cursor[v.w], 1); edge_list[p3] = e0 + 3;
}

// ---------------------------------------------------------------------------
// Gather: one wave per node, h written as bf16.
// Edge ids prefetched 64-at-a-time coalesced then shfl'd out; rbf row loaded
// as 3x float2 (8B-aligned: rows are 24B) instead of 6 scalars -> per-edge
// VMEM instruction count drops 7 -> 4. Nontemporal on all read-once streams.
// ---------------------------------------------------------------------------
__global__ __launch_bounds__(256) void gather_nodes(
    const float* __restrict__ x, const float* __restrict__ rbf,
    const int* __restrict__ edge_list, const int* __restrict__ offsets,
    const float* __restrict__ wrbf, short* __restrict__ h16)
{
    int node = blockIdx.x * 4 + (threadIdx.x >> 6);
    if (node >= N_NODES) return;
    int lane = threadIdx.x & 63;

    const floatx4* wr4 = (const floatx4*)wrbf;   // [6][64] float4
    floatx4 wr[6];
#pragma unroll
    for (int k = 0; k < 6; k++) wr[k] = wr4[k * 64 + lane];

    int beg = offsets[node], end = offsets[node + 1];
    floatx4 acc = {0.f, 0.f, 0.f, 0.f};
    for (int j0 = beg; j0 < end; j0 += 64) {
        int myid = (j0 + lane < end)
                 ? __builtin_nontemporal_load(&edge_list[j0 + lane]) : 0;
        int cnt  = end - j0; if (cnt > 64) cnt = 64;
#pragma unroll 2
        for (int g = 0; g < cnt; g++) {
            int e = __shfl(myid, g);
            const float* rp = rbf + e * 6;
            floatx2 r01 = __builtin_nontemporal_load((const floatx2*)(rp + 0));
            floatx2 r23 = __builtin_nontemporal_load((const floatx2*)(rp + 2));
            floatx2 r45 = __builtin_nontemporal_load((const floatx2*)(rp + 4));
            floatx4 xv = __builtin_nontemporal_load(
                &((const floatx4*)x)[(size_t)e * 64 + lane]);
            floatx4 p = r01[0] * wr[0] + r01[1] * wr[1] + r23[0] * wr[2]
                      + r23[1] * wr[3] + r45[0] * wr[4] + r45[1] * wr[5];
            acc += p * xv;
        }
    }
    shortx4 s4 = { f2bf(acc.x), f2bf(acc.y), f2bf(acc.z), f2bf(acc.w) };
    ((shortx4*)h16)[(size_t)node * 64 + lane] = s4;
}

// ---------------------------------------------------------------------------
// Fused MLP: one (a, 64-row tile) per block. Single 33.8 KB LDS buffer,
// h read as bf16, vectorized LDS reads in the output projection.
// ---------------------------------------------------------------------------
__global__ __launch_bounds__(256, 2) void mlp_kernel(
    const short* __restrict__ h16, const short* __restrict__ wfrag,
    const float* __restrict__ bias, const float* __restrict__ wout,
    float* __restrict__ out)
{
    __shared__ __align__(16) short ylds[64 * 264];
    const int t = threadIdx.x;
    const int wave = t >> 6, lane = t & 63, q = lane >> 4, c15 = lane & 15;
    const int a  = blockIdx.x & 1;
    const int n0 = (blockIdx.x >> 1) * 64;

    // stage h tile (already bf16) into LDS
#pragma unroll
    for (int j = 0; j < 8; j++) {
        int grp = t + j * 256;
        int r = grp >> 5, c8 = grp & 31;
        shortx8 v = {0, 0, 0, 0, 0, 0, 0, 0};
        if (n0 + r < N_NODES)
            v = *(const shortx8*)&h16[(size_t)(n0 + r) * 256 + c8 * 8];
        *(shortx8*)&ylds[r * 264 + c8 * 8] = v;
    }
    __syncthreads();

    for (int lay = 0; lay < 4; lay++) {
        const bf16x8* wf = (const bf16x8*)(wfrag + (size_t)(a * 4 + lay) * 65536);
        floatx4 acc[4][4];
#pragma unroll
        for (int mt = 0; mt < 4; mt++)
#pragma unroll
            for (int nt = 0; nt < 4; nt++)
                acc[mt][nt] = (floatx4){0.f, 0.f, 0.f, 0.f};

#pragma unroll
        for (int ks = 0; ks < 8; ks++) {
            bf16x8 bfr[4];
#pragma unroll
            for (int nt = 0; nt < 4; nt++)
                bfr[nt] = wf[(ks * 16 + wave * 4 + nt) * 64 + lane];
#pragma unroll
            for (int mt = 0; mt < 4; mt++) {
                bf16x8 afr = *(const bf16x8*)&ylds[(mt * 16 + c15) * 264 + ks * 32 + q * 8];
#pragma unroll
                for (int nt = 0; nt < 4; nt++)
                    acc[mt][nt] = __builtin_amdgcn_mfma_f32_16x16x32_bf16(
                        afr, bfr[nt], acc[mt][nt], 0, 0, 0);
            }
        }
        __syncthreads();              // all reads done before overwrite

        float bv[4];
#pragma unroll
        for (int nt = 0; nt < 4; nt++)
            bv[nt] = (lay >= 1)
                   ? bias[(a * 3 + lay - 1) * 256 + wave * 64 + nt * 16 + c15]
                   : 0.0f;
#pragma unroll
        for (int mt = 0; mt < 4; mt++)
#pragma unroll
            for (int nt = 0; nt < 4; nt++)
#pragma unroll
                for (int rg = 0; rg < 4; rg++) {
                    float v = acc[mt][nt][rg] + bv[nt];
                    if (lay >= 1) v = v / (1.0f + __expf(-v));   // SiLU
                    ylds[(mt * 16 + q * 4 + rg) * 264 + wave * 64 + nt * 16 + c15] = f2bf(v);
                }
        __syncthreads();
    }

    // output projection: y3[64][256] . wout[a][256], vectorized LDS reads
    {
        int r  = wave * 16 + (lane >> 2);
        int cq = lane & 3;
        const float* wo = wout + a * 256 + cq * 64;
        const short* yp = &ylds[r * 264 + cq * 64];
        float s = 0.0f;
#pragma unroll
        for (int bb = 0; bb < 8; bb++) {
            shortx8 v = *(const shortx8*)&yp[bb * 8];
#pragma unroll
            for (int j = 0; j < 8; j++) s += bf2f(v[j]) * wo[bb * 8 + j];
        }
        s += __shfl_xor(s, 1);
        s += __shfl_xor(s, 2);
        if (cq == 0 && n0 + r < N_NODES) out[a * N_NODES + n0 + r] = s;
    }
}

// ---------------------------------------------------------------------------
extern "C" void kernel_launch(void* const* d_in, const int* in_sizes, int n_in,
                              void* d_out, int out_size, void* d_ws, size_t ws_size,
                              hipStream_t stream)
{
    (void)in_sizes; (void)n_in; (void)out_size; (void)ws_size;
    const float* x    = (const float*)d_in[0];
    const float* rbf  = (const float*)d_in[1];
    const int*   idx  = (const int*)d_in[2];
    const float* wrbf = (const float*)d_in[4];
    const float* wup  = (const float*)d_in[5];
    const float* whid = (const float*)d_in[6];
    const float* bias = (const float*)d_in[7];
    const float* wout = (const float*)d_in[8];
    float* out = (float*)d_out;

    char* ws = (char*)d_ws;
    short* h16       = (short*)ws;  ws += (size_t)N_NODES * H_DIM * sizeof(short);
    short* wfrag     = (short*)ws;  ws += (size_t)8 * 65536 * sizeof(short);
    int*   counts    = (int*)ws;    ws += (size_t)N_NODES * sizeof(int);
    int*   offsets   = (int*)ws;    ws += (size_t)(N_NODES + 1) * sizeof(int);
    int*   cursor    = (int*)ws;    ws += (size_t)N_NODES * sizeof(int);
    int*   edge_list = (int*)ws;

    hipMemsetAsync(counts, 0, (size_t)N_NODES * sizeof(int), stream);
    // prep (256 blocks) + hist (489 blocks) fused, independent block ranges
    prep_hist<<<256 + (E_EDGES / 4 + 255) / 256, 256, 0, stream>>>(
        wup, whid, wfrag, idx, counts);
    scan_kernel<<<1, 1024, 0, stream>>>(counts, offsets, cursor);
    scatter_ids<<<(E_EDGES / 4 + 255) / 256, 256, 0, stream>>>(idx, cursor, edge_list);
    gather_nodes<<<(N_NODES + 3) / 4, 256, 0, stream>>>(x, rbf, edge_list, offsets, wrbf, h16);
    mlp_kernel<<<938, 256, 0, stream>>>(h16, wfrag, bias, wout, out);
}